// Round 1
// baseline (608.821 us; speedup 1.0000x reference)
//
#include <hip/hip_runtime.h>
#include <hip/hip_bf16.h>

// ---------- types ----------
typedef __bf16 bf16x8 __attribute__((ext_vector_type(8)));
typedef float  f32x4  __attribute__((ext_vector_type(4)));
typedef unsigned short u16;

__device__ __forceinline__ u16 f2bf(float f) {
    __hip_bfloat16 h = __float2bfloat16(f);   // RNE
    return __builtin_bit_cast(unsigned short, h);
}
__device__ __forceinline__ float bf2f(u16 u) {
    return __bfloat162float(__builtin_bit_cast(__hip_bfloat16, u));
}

// mode: 0=sum, 1=max, 2=min   (256-thread blocks = 4 waves)
template <int MODE>
__device__ __forceinline__ float blockReduce(float v, float* sbuf) {
    #pragma unroll
    for (int off = 32; off > 0; off >>= 1) {
        float o = __shfl_down(v, off, 64);
        v = (MODE == 0) ? v + o : (MODE == 1) ? fmaxf(v, o) : fminf(v, o);
    }
    int lane = threadIdx.x & 63, w = threadIdx.x >> 6;
    __syncthreads();                 // protect sbuf from previous use
    if (lane == 0) sbuf[w] = v;
    __syncthreads();
    float r = sbuf[0];
    #pragma unroll
    for (int i = 1; i < 4; ++i) {
        float o = sbuf[i];
        r = (MODE == 0) ? r + o : (MODE == 1) ? fmaxf(r, o) : fminf(r, o);
    }
    return r;
}

// ---------- prep: x fp32 -> xh bf16 + xsq + fp32 passthrough to out_x ----------
__global__ void convert_x(const float* __restrict__ src, u16* __restrict__ dst,
                          float* __restrict__ rowsq, float* __restrict__ copyOut) {
    __shared__ float sbuf[4];
    int r = blockIdx.x, t = threadIdx.x;
    size_t base = (size_t)r * 2048 + t * 8;
    float4 a0 = *(const float4*)(src + base);
    float4 a1 = *(const float4*)(src + base + 4);
    float ss = a0.x*a0.x + a0.y*a0.y + a0.z*a0.z + a0.w*a0.w
             + a1.x*a1.x + a1.y*a1.y + a1.z*a1.z + a1.w*a1.w;
    ushort4 u0, u1;
    u0.x = f2bf(a0.x); u0.y = f2bf(a0.y); u0.z = f2bf(a0.z); u0.w = f2bf(a0.w);
    u1.x = f2bf(a1.x); u1.y = f2bf(a1.y); u1.z = f2bf(a1.z); u1.w = f2bf(a1.w);
    *(ushort4*)(dst + base)     = u0;
    *(ushort4*)(dst + base + 4) = u1;
    *(float4*)(copyOut + base)     = a0;
    *(float4*)(copyOut + base + 4) = a1;
    ss = blockReduce<0>(ss, sbuf);
    if (t == 0) rowsq[r] = ss;
}

// ---------- prep: merged weight convert -> Bp [4096,2048] bf16 ----------
// rows 0..1023 = cent (valid<1000, csq), 1024..2047 = W_hall (valid<1000), 2048..4095 = W_sel
__global__ void convert_weights(const float* __restrict__ cent, const float* __restrict__ whall,
                                const float* __restrict__ wsel, u16* __restrict__ Bp,
                                float* __restrict__ csq) {
    __shared__ float sbuf[4];
    int r = blockIdx.x, t = threadIdx.x;
    const float* src; int sr; bool valid;
    if (r < 1024)       { src = cent;  sr = r;        valid = sr < 1000; }
    else if (r < 2048)  { src = whall; sr = r - 1024; valid = sr < 1000; }
    else                { src = wsel;  sr = r - 2048; valid = true; }
    size_t dbase = (size_t)r * 2048 + t * 8;
    float ss = 0.f;
    ushort4 u0 = {0,0,0,0}, u1 = {0,0,0,0};
    if (valid) {
        size_t sbase = (size_t)sr * 2048 + t * 8;
        float4 a0 = *(const float4*)(src + sbase);
        float4 a1 = *(const float4*)(src + sbase + 4);
        ss = a0.x*a0.x + a0.y*a0.y + a0.z*a0.z + a0.w*a0.w
           + a1.x*a1.x + a1.y*a1.y + a1.z*a1.z + a1.w*a1.w;
        u0.x = f2bf(a0.x); u0.y = f2bf(a0.y); u0.z = f2bf(a0.z); u0.w = f2bf(a0.w);
        u1.x = f2bf(a1.x); u1.y = f2bf(a1.y); u1.z = f2bf(a1.z); u1.w = f2bf(a1.w);
    }
    *(ushort4*)(Bp + dbase)     = u0;
    *(ushort4*)(Bp + dbase + 4) = u1;
    if (r < 1024) {
        ss = blockReduce<0>(ss, sbuf);
        if (t == 0) csq[r] = ss;
    }
}

// ---------- prep: W_cos row-normalize -> bf16, zero-pad rows ----------
__global__ void norm_rows(const float* __restrict__ src, u16* __restrict__ dst, int validRows) {
    __shared__ float sbuf[4];
    int r = blockIdx.x, t = threadIdx.x;
    size_t base = (size_t)r * 2048 + t * 8;
    ushort4 u0 = {0,0,0,0}, u1 = {0,0,0,0};
    if (r < validRows) {
        float4 a0 = *(const float4*)(src + base);
        float4 a1 = *(const float4*)(src + base + 4);
        float ss = a0.x*a0.x + a0.y*a0.y + a0.z*a0.z + a0.w*a0.w
                 + a1.x*a1.x + a1.y*a1.y + a1.z*a1.z + a1.w*a1.w;
        ss = blockReduce<0>(ss, sbuf);
        float sc = 1.f / sqrtf(ss);
        u0.x = f2bf(a0.x*sc); u0.y = f2bf(a0.y*sc); u0.z = f2bf(a0.z*sc); u0.w = f2bf(a0.w*sc);
        u1.x = f2bf(a1.x*sc); u1.y = f2bf(a1.y*sc); u1.z = f2bf(a1.z*sc); u1.w = f2bf(a1.w*sc);
    }
    *(ushort4*)(dst + base)     = u0;
    *(ushort4*)(dst + base + 4) = u1;
}

// ---------- prep: centroids [1000,2048] fp32 -> centT [2048,1024] bf16 (transposed, K-padded) ----------
__global__ void transpose_to_bf16(const float* __restrict__ src, u16* __restrict__ dst, int validRows) {
    __shared__ u16 tile[32][33];
    int d0 = blockIdx.x * 32;   // feature base (src col)
    int c0 = blockIdx.y * 32;   // class base  (src row)
    int tx = threadIdx.x, ty = threadIdx.y;
    #pragma unroll
    for (int k = 0; k < 4; ++k) {
        int c = c0 + ty + k * 8;
        float v = (c < validRows) ? src[(size_t)c * 2048 + d0 + tx] : 0.f;
        tile[ty + k * 8][tx] = f2bf(v);
    }
    __syncthreads();
    #pragma unroll
    for (int k = 0; k < 4; ++k) {
        int d = d0 + ty + k * 8;
        dst[(size_t)d * 1024 + c0 + tx] = tile[tx][ty + k * 8];
    }
}

// ================= 256x256-tile 8-phase-style GEMM (T2+T3+T4+T5) =================
// C[M,N] = A[M,K]bf16 @ Bt[N,K]bf16^T, fp32 accum.
// 512 threads = 8 waves (2M x 4N), per-wave output 128x64 (acc[8][4] of 16x16).
// BK=32, 4-deep circular K-tile LDS buffers (4 x (A 16KB + B 16KB) = 128 KiB).
// Per K-tile: 2 phases of {ds_read subtile; 2x global_load_lds; barrier;
// lgkmcnt(0); setprio(1); 16 MFMA; setprio(0); barrier}. Counted s_waitcnt
// vmcnt(6) once per K-tile (never 0 in main loop): tile t's loads are issued at
// K-tile t-3 (4 phases of slack); at end of (t-1).B the newest 6 outstanding
// loads are {(t-1).B, (t-1).A, (t-2).B} so tile t (and older) has landed.
// LDS layout [256 rows][32 elems]; 16B granule g of row r holds logical granule
// g ^ ((r>>1)&3): same involution pre-applied to the global source (rule #21),
// giving balanced (2-lane/bank-cycle) ds_read_b128. K accumulation order is
// identical to the 128^2 kernel (sequential 32-K MFMAs) -> bitwise-same output.
// EPI 1: bf16 store to Cb
// EPI 2: acc = memf; inf = tanh(sel+b)*acc -> Cf; fused=reach*(xh+inf) -> fusedh
template <int EPI>
__global__ __launch_bounds__(512, 2)
void gemm256(const u16* __restrict__ A, const u16* __restrict__ Bt,
             float* __restrict__ Cf, u16* __restrict__ Cb,
             int K, int ldc,
             const float* __restrict__ bias,
             const u16* __restrict__ selp, int ldsel,
             const float* __restrict__ reach, const u16* __restrict__ xh2,
             u16* __restrict__ fusedh) {
    __shared__ u16 As[4][256 * 32];
    __shared__ u16 Bs[4][256 * 32];

    const int tid  = threadIdx.x;
    const int lane = tid & 63;
    const int w    = tid >> 6;            // wave 0..7
    const int wr   = w >> 2;              // 0..1  (row half of 256)
    const int wc   = w & 3;               // 0..3  (col quarter of 256)
    const int quad = lane >> 4, r16 = lane & 15;
    // compute-side read offset (elems): row r16, logical k-granule=quad, swizzled
    const int rdOff = r16 * 32 + ((quad ^ ((r16 >> 1) & 3)) * 8);

    // staging lane decomposition: 64 lanes x 16B = 16 rows x 4 granules
    const int lr = lane >> 2;             // 0..15 row within wave chunk
    const int lc = lane & 3;              // 0..3  physical granule slot
    const int skel = (lc ^ ((lr >> 1) & 3)) * 8;   // pre-swizzled k-elem offset

    const size_t rowBase = (size_t)blockIdx.y * 256;
    const size_t colBase = (size_t)blockIdx.x * 256;

    const u16* aSrc = A  + (rowBase + (size_t)(w * 16 + lr)) * K + skel;
    const u16* bSrc = Bt + (colBase + (size_t)(w * 16 + lr)) * K + skel;
    const int ldsRowBase = (w * 16) * 32;  // wave-uniform elem offset

    const int NT = K >> 5;                 // K-tiles of 32

    f32x4 acc[8][4] = {};

    // one K-tile of one operand = 2 issues x (512 lanes x 16B) = 16 KB (256x32)
    auto stage = [&](const u16* srcBase, u16* ldsArr, int srcTile) {
        #pragma unroll
        for (int j = 0; j < 2; ++j) {
            const u16* src = srcBase + (size_t)(j * 128) * K + srcTile * 32;
            __builtin_amdgcn_global_load_lds(
                (const __attribute__((address_space(1))) void*)src,
                (__attribute__((address_space(3))) void*)(ldsArr + j * (128 * 32) + ldsRowBase),
                16, 0, 0);
        }
    };

    // ---- prologue: stage K-tiles 0,1,2 (12 loads/thread), keep 1,2 in flight ----
    #pragma unroll
    for (int pt = 0; pt < 3; ++pt) {
        stage(aSrc, As[pt], pt);
        stage(bSrc, Bs[pt], pt);
    }
    asm volatile("s_waitcnt vmcnt(8)" ::: "memory");  // tile 0 landed (newest 8 = tiles 1,2)
    __builtin_amdgcn_s_barrier();

    for (int t = 0; t < NT; ++t) {
        const int bi = t & 3;
        const int nt3 = t + 3;
        const int sbi = nt3 & 3;
        // tail: keep issuing (dummy tile 0) so the fixed vmcnt(6) accounting
        // stays valid; buffer (t+3)&3 is never read again once nt3 >= NT.
        const int srcTile = (nt3 < NT) ? nt3 : 0;
        bf16x8 a[4], b[4];

        // ===== phase A: row-half 0, all 4 B col-frags =====
        #pragma unroll
        for (int fi = 0; fi < 4; ++fi)
            a[fi] = *(const bf16x8*)&As[bi][(wr * 128 + fi * 16) * 32 + rdOff];
        #pragma unroll
        for (int fj = 0; fj < 4; ++fj)
            b[fj] = *(const bf16x8*)&Bs[bi][(wc * 64 + fj * 16) * 32 + rdOff];
        stage(aSrc, As[sbi], srcTile);
        __builtin_amdgcn_s_barrier();
        asm volatile("s_waitcnt lgkmcnt(0)" ::: "memory");
        __builtin_amdgcn_sched_barrier(0);
        __builtin_amdgcn_s_setprio(1);
        #pragma unroll
        for (int fi = 0; fi < 4; ++fi)
            #pragma unroll
            for (int fj = 0; fj < 4; ++fj)
                acc[fi][fj] = __builtin_amdgcn_mfma_f32_16x16x32_bf16(a[fi], b[fj], acc[fi][fj], 0, 0, 0);
        __builtin_amdgcn_s_setprio(0);
        __builtin_amdgcn_s_barrier();

        // ===== phase B: row-half 1 (B frags reused from registers) =====
        #pragma unroll
        for (int fi = 0; fi < 4; ++fi)
            a[fi] = *(const bf16x8*)&As[bi][(wr * 128 + 64 + fi * 16) * 32 + rdOff];
        stage(bSrc, Bs[sbi], srcTile);
        __builtin_amdgcn_s_barrier();
        asm volatile("s_waitcnt lgkmcnt(0)" ::: "memory");
        __builtin_amdgcn_sched_barrier(0);
        __builtin_amdgcn_s_setprio(1);
        #pragma unroll
        for (int fi = 0; fi < 4; ++fi)
            #pragma unroll
            for (int fj = 0; fj < 4; ++fj)
                acc[4 + fi][fj] = __builtin_amdgcn_mfma_f32_16x16x32_bf16(a[fi], b[fj], acc[4 + fi][fj], 0, 0, 0);
        __builtin_amdgcn_s_setprio(0);
        asm volatile("s_waitcnt vmcnt(6)" ::: "memory");  // counted, never 0
        __builtin_amdgcn_s_barrier();
    }

    // epilogue: C/D layout col=lane&15, row=quad*4+reg (verified m89/m91)
    #pragma unroll
    for (int i = 0; i < 8; ++i) {
        #pragma unroll
        for (int j = 0; j < 4; ++j) {
            #pragma unroll
            for (int v = 0; v < 4; ++v) {
                size_t grow = rowBase + wr * 128 + i * 16 + quad * 4 + v;
                size_t gcol = colBase + wc * 64 + j * 16 + r16;
                float val = acc[i][j][v];
                if (EPI == 1) {
                    Cb[grow * (size_t)ldc + gcol] = f2bf(val);
                } else if (EPI == 2) {
                    float sv  = bf2f(selp[grow * (size_t)ldsel + gcol]);
                    float tnh = tanhf(sv + bias[gcol]);
                    float inf = tnh * val;
                    Cf[grow * (size_t)ldc + gcol] = inf;
                    float xv = bf2f(xh2[grow * (size_t)ldc + gcol]);
                    fusedh[grow * (size_t)ldc + gcol] = f2bf(reach[grow] * (xv + inf));
                }
            }
        }
    }
}

// ---------- GEMM: 128x128-tile 2-phase kernel (kept for GEMM-C: N=1024 grid) ----------
template <int EPI>
__global__ __launch_bounds__(256, 4)
void gemm_bt(const u16* __restrict__ A, const u16* __restrict__ Bt,
             float* __restrict__ Cf, u16* __restrict__ Cb,
             int K, int ldc, int nValid,
             const float* __restrict__ bias,
             const u16* __restrict__ selp, int ldsel,
             const float* __restrict__ reach, const u16* __restrict__ xh2,
             u16* __restrict__ fusedh) {
    __shared__ u16 As[128 * 64];
    __shared__ u16 Bs[128 * 64];
    const int tid  = threadIdx.x;
    const int lane = tid & 63;
    const int w    = tid >> 6;
    const int wr   = w >> 1, wc = w & 1;
    const int quad = lane >> 4, r16 = lane & 15;
    const int sw   = r16 & 7;            // reader swizzle key
    const int lr   = lane >> 3;          // staging: row within 8-row chunk (0..7)
    const int lc   = lane & 7;           // staging: physical granule slot (0..7)
    const int lk   = (lc ^ lr) * 8;      // staging: swizzled logical k elem offset
    const size_t rowBase = (size_t)blockIdx.y * 128;
    const size_t colBase = (size_t)blockIdx.x * 128;

    f32x4 acc[4][4] = {};

    for (int kt = 0; kt < K; kt += 64) {
        #pragma unroll
        for (int i = 0; i < 4; ++i) {
            int ci = w * 4 + i;   // chunk 0..15, 8 rows each
            const u16* ga = A  + (rowBase + ci * 8 + lr) * (size_t)K + kt + lk;
            const u16* gb = Bt + (colBase + ci * 8 + lr) * (size_t)K + kt + lk;
            __builtin_amdgcn_global_load_lds(
                (const __attribute__((address_space(1))) void*)ga,
                (__attribute__((address_space(3))) void*)(As + ci * 512), 16, 0, 0);
            __builtin_amdgcn_global_load_lds(
                (const __attribute__((address_space(1))) void*)gb,
                (__attribute__((address_space(3))) void*)(Bs + ci * 512), 16, 0, 0);
        }
        __syncthreads();
        #pragma unroll
        for (int kk2 = 0; kk2 < 2; ++kk2) {
            const int off = (((kk2 << 2) | quad) ^ sw) * 8;
            bf16x8 a[4], b[4];
            #pragma unroll
            for (int i = 0; i < 4; ++i)
                a[i] = *(const bf16x8*)(As + (wr * 64 + i * 16 + r16) * 64 + off);
            #pragma unroll
            for (int j = 0; j < 4; ++j)
                b[j] = *(const bf16x8*)(Bs + (wc * 64 + j * 16 + r16) * 64 + off);
            #pragma unroll
            for (int i = 0; i < 4; ++i)
                #pragma unroll
                for (int j = 0; j < 4; ++j)
                    acc[i][j] = __builtin_amdgcn_mfma_f32_16x16x32_bf16(a[i], b[j], acc[i][j], 0, 0, 0);
        }
        __syncthreads();
    }

    #pragma unroll
    for (int i = 0; i < 4; ++i) {
        #pragma unroll
        for (int j = 0; j < 4; ++j) {
            #pragma unroll
            for (int v = 0; v < 4; ++v) {
                size_t grow = rowBase + wr * 64 + i * 16 + quad * 4 + v;
                size_t gcol = colBase + wc * 64 + j * 16 + r16;
                float val = acc[i][j][v];
                if (EPI == 1) {
                    Cb[grow * (size_t)ldc + gcol] = f2bf(val);
                } else if (EPI == 2) {
                    float sv  = bf2f(selp[grow * (size_t)ldsel + gcol]);
                    float t   = tanhf(sv + bias[gcol]);
                    float inf = t * val;
                    Cf[grow * (size_t)ldc + gcol] = inf;
                    float xv = bf2f(xh2[grow * (size_t)ldc + gcol]);
                    fusedh[grow * (size_t)ldc + gcol] = f2bf(reach[grow] * (xv + inf));
                } else if (EPI == 3) {
                    if ((int)gcol < nValid) Cf[grow * (size_t)ldc + gcol] = bias[grow] * val;
                }
            }
        }
    }
}

// ---------- merged: min distance -> reachability, softmax -> Vm ----------
// Sp is [B,4096] bf16: cols 0..999 = x.cent, 1024..2023 = x.W_hall (2048..4095 = sel, unused here)
__global__ void min_softmax(const u16* __restrict__ Sp, const float* __restrict__ xsq,
                            const float* __restrict__ csq, const float* __restrict__ bh,
                            float* __restrict__ reach, u16* __restrict__ Vm) {
    __shared__ float sbuf[4];
    int r = blockIdx.x, t = threadIdx.x;
    size_t rb = (size_t)r * 4096;
    // --- min distance ---
    float m = 1e30f;
    for (int c = t; c < 1000; c += 256)
        m = fminf(m, csq[c] - 2.f * bf2f(Sp[rb + c]));
    m = blockReduce<2>(m, sbuf);
    if (t == 0) {
        float d2 = xsq[r] + m;
        reach[r] = 10.f / sqrtf(fmaxf(d2, 0.f));
    }
    // --- softmax over 1000 classes ---
    float l[4];
    float mx = -1e30f;
    #pragma unroll
    for (int i = 0; i < 4; ++i) {
        int c = t + i * 256;
        l[i] = (c < 1000) ? (bf2f(Sp[rb + 1024 + c]) + bh[c]) : -1e30f;
        mx = fmaxf(mx, l[i]);
    }
    mx = blockReduce<1>(mx, sbuf);
    float s = 0.f;
    #pragma unroll
    for (int i = 0; i < 4; ++i) {
        int c = t + i * 256;
        l[i] = (c < 1000) ? expf(l[i] - mx) : 0.f;
        s += l[i];
    }
    s = blockReduce<0>(s, sbuf);
    float inv = 1.f / s;
    #pragma unroll
    for (int i = 0; i < 4; ++i) {
        int c = t + i * 256;
        Vm[(size_t)r * 1024 + c] = f2bf(l[i] * inv);
    }
}

// ---------- per-row CosNorm scale: scale[r] = 16/(1+||fused_r||) ----------
__global__ void rowsq_scale(const u16* __restrict__ fusedh, float* __restrict__ scale) {
    __shared__ float sbuf[4];
    int r = blockIdx.x, t = threadIdx.x;
    size_t base = (size_t)r * 2048 + t * 8;
    ushort4 u0 = *(const ushort4*)(fusedh + base);
    ushort4 u1 = *(const ushort4*)(fusedh + base + 4);
    float f0 = bf2f(u0.x), f1 = bf2f(u0.y), f2 = bf2f(u0.z), f3 = bf2f(u0.w);
    float f4 = bf2f(u1.x), f5 = bf2f(u1.y), f6 = bf2f(u1.z), f7 = bf2f(u1.w);
    float ss = f0*f0 + f1*f1 + f2*f2 + f3*f3 + f4*f4 + f5*f5 + f6*f6 + f7*f7;
    ss = blockReduce<0>(ss, sbuf);
    if (t == 0) scale[r] = 16.f / (1.f + sqrtf(ss));
}

extern "C" void kernel_launch(void* const* d_in, const int* in_sizes, int n_in,
                              void* d_out, int out_size, void* d_ws, size_t ws_size,
                              hipStream_t stream) {
    const float* x      = (const float*)d_in[0];   // [8192,2048]
    const float* cent   = (const float*)d_in[1];   // [1000,2048]
    const float* W_hall = (const float*)d_in[2];   // [1000,2048]
    const float* b_hall = (const float*)d_in[3];   // [1000]
    const float* W_sel  = (const float*)d_in[4];   // [2048,2048]
    const float* b_sel  = (const float*)d_in[5];   // [2048]
    const float* W_cos  = (const float*)d_in[6];   // [1000,2048]

    float* out_logits = (float*)d_out;                          // [8192,1000]
    float* out_x      = out_logits + (size_t)8192 * 1000;       // [8192,2048]
    float* out_inf    = out_x      + (size_t)8192 * 2048;       // [8192,2048]

    char* ws = (char*)d_ws;
    u16*   xh     = (u16*)  (ws);                  // 33554432 B  [8192,2048] bf16
    u16*   Bp     = (u16*)  (ws + 33554432);       // 16777216 B  [4096,2048] bf16: cent|W_hall|W_sel
    u16*   ew     = (u16*)  (ws + 50331648);       //  4194304 B  [1024,2048]
    u16*   centT  = (u16*)  (ws + 54525952);       //  4194304 B  [2048,1024]
    u16*   Sp     = (u16*)  (ws + 58720256);       // 67108864 B  [8192,4096] bf16 (dot|H|sel)
    u16*   Vm     = (u16*)  (ws + 125829120);      // 16777216 B  [8192,1024] bf16
    u16*   fusedh = (u16*)  (ws + 142606336);      // 33554432 B  [8192,2048] bf16
    float* xsq    = (float*)(ws + 176160768);      //    32768 B
    float* csq    = (float*)(ws + 176193536);      //     4096 B
    float* reach  = (float*)(ws + 176197632);      //    32768 B
    float* scale  = (float*)(ws + 176230400);      //    32768 B

    (void)in_sizes; (void)n_in; (void)out_size; (void)ws_size;

    // prep (convert_x also streams the fp32 passthrough to out_x: direct_feature)
    convert_x<<<8192, 256, 0, stream>>>(x, xh, xsq, out_x);
    convert_weights<<<4096, 256, 0, stream>>>(cent, W_hall, W_sel, Bp, csq);
    norm_rows<<<1024, 256, 0, stream>>>(W_cos, ew, 1000);
    transpose_to_bf16<<<dim3(64, 32), dim3(32, 8), 0, stream>>>(cent, centT, 1000);

    // GEMM-A: Sp = x @ [cent | W_hall | W_sel]^T  (M=8192, N=4096, K=2048, bf16 out)
    gemm256<1><<<dim3(16, 32), 512, 0, stream>>>(xh, Bp, nullptr, Sp, 2048, 4096,
                                                 nullptr, nullptr, 0, nullptr, nullptr, nullptr);
    min_softmax<<<8192, 256, 0, stream>>>(Sp, xsq, csq, b_hall, reach, Vm);

    // GEMM-B: acc = Vm @ cent (memf); epilogue: inf=tanh(sel+b_sel)*acc -> out_inf,
    //         fused=reach*(x+inf) -> fusedh   (M=8192, N=2048, K=1024)
    gemm256<2><<<dim3(8, 32), 512, 0, stream>>>(Vm, centT, out_inf, nullptr, 1024, 2048,
                                                b_sel, Sp + 2048, 4096, reach, xh, fusedh);

    // per-row CosNorm scale
    rowsq_scale<<<8192, 256, 0, stream>>>(fusedh, scale);

    // GEMM-C: logits = scale[row] * (fused @ ew^T)  (N=1024 -> only 128 blocks of
    // 256^2 tiles would idle half the CUs; keep the 128^2 kernel here)
    gemm_bt<3><<<dim3(8, 64), 256, 0, stream>>>(fusedh, ew, out_logits, nullptr, 2048, 1000, 1000,
                                                scale, nullptr, 0, nullptr, nullptr, nullptr);
}

// Round 2
// 562.097 us; speedup vs baseline: 1.0831x; 1.0831x over previous
//
#include <hip/hip_runtime.h>
#include <hip/hip_bf16.h>

// ---------- types ----------
typedef __bf16 bf16x8 __attribute__((ext_vector_type(8)));
typedef float  f32x4  __attribute__((ext_vector_type(4)));
typedef unsigned short u16;

__device__ __forceinline__ u16 f2bf(float f) {
    __hip_bfloat16 h = __float2bfloat16(f);   // RNE
    return __builtin_bit_cast(unsigned short, h);
}
__device__ __forceinline__ float bf2f(u16 u) {
    return __bfloat162float(__builtin_bit_cast(__hip_bfloat16, u));
}

// mode: 0=sum, 1=max, 2=min   (256-thread blocks = 4 waves)
template <int MODE>
__device__ __forceinline__ float blockReduce(float v, float* sbuf) {
    #pragma unroll
    for (int off = 32; off > 0; off >>= 1) {
        float o = __shfl_down(v, off, 64);
        v = (MODE == 0) ? v + o : (MODE == 1) ? fmaxf(v, o) : fminf(v, o);
    }
    int lane = threadIdx.x & 63, w = threadIdx.x >> 6;
    __syncthreads();                 // protect sbuf from previous use
    if (lane == 0) sbuf[w] = v;
    __syncthreads();
    float r = sbuf[0];
    #pragma unroll
    for (int i = 1; i < 4; ++i) {
        float o = sbuf[i];
        r = (MODE == 0) ? r + o : (MODE == 1) ? fmaxf(r, o) : fminf(r, o);
    }
    return r;
}

// ---------- prep: x fp32 -> xh bf16 + xsq + fp32 passthrough to out_x ----------
__global__ void convert_x(const float* __restrict__ src, u16* __restrict__ dst,
                          float* __restrict__ rowsq, float* __restrict__ copyOut) {
    __shared__ float sbuf[4];
    int r = blockIdx.x, t = threadIdx.x;
    size_t base = (size_t)r * 2048 + t * 8;
    float4 a0 = *(const float4*)(src + base);
    float4 a1 = *(const float4*)(src + base + 4);
    float ss = a0.x*a0.x + a0.y*a0.y + a0.z*a0.z + a0.w*a0.w
             + a1.x*a1.x + a1.y*a1.y + a1.z*a1.z + a1.w*a1.w;
    ushort4 u0, u1;
    u0.x = f2bf(a0.x); u0.y = f2bf(a0.y); u0.z = f2bf(a0.z); u0.w = f2bf(a0.w);
    u1.x = f2bf(a1.x); u1.y = f2bf(a1.y); u1.z = f2bf(a1.z); u1.w = f2bf(a1.w);
    *(ushort4*)(dst + base)     = u0;
    *(ushort4*)(dst + base + 4) = u1;
    *(float4*)(copyOut + base)     = a0;
    *(float4*)(copyOut + base + 4) = a1;
    ss = blockReduce<0>(ss, sbuf);
    if (t == 0) rowsq[r] = ss;
}

// ---------- prep: merged weight convert -> Bp [4096,2048] bf16 ----------
// rows 0..1023 = cent (valid<1000, csq), 1024..2047 = W_hall (valid<1000), 2048..4095 = W_sel
__global__ void convert_weights(const float* __restrict__ cent, const float* __restrict__ whall,
                                const float* __restrict__ wsel, u16* __restrict__ Bp,
                                float* __restrict__ csq) {
    __shared__ float sbuf[4];
    int r = blockIdx.x, t = threadIdx.x;
    const float* src; int sr; bool valid;
    if (r < 1024)       { src = cent;  sr = r;        valid = sr < 1000; }
    else if (r < 2048)  { src = whall; sr = r - 1024; valid = sr < 1000; }
    else                { src = wsel;  sr = r - 2048; valid = true; }
    size_t dbase = (size_t)r * 2048 + t * 8;
    float ss = 0.f;
    ushort4 u0 = {0,0,0,0}, u1 = {0,0,0,0};
    if (valid) {
        size_t sbase = (size_t)sr * 2048 + t * 8;
        float4 a0 = *(const float4*)(src + sbase);
        float4 a1 = *(const float4*)(src + sbase + 4);
        ss = a0.x*a0.x + a0.y*a0.y + a0.z*a0.z + a0.w*a0.w
           + a1.x*a1.x + a1.y*a1.y + a1.z*a1.z + a1.w*a1.w;
        u0.x = f2bf(a0.x); u0.y = f2bf(a0.y); u0.z = f2bf(a0.z); u0.w = f2bf(a0.w);
        u1.x = f2bf(a1.x); u1.y = f2bf(a1.y); u1.z = f2bf(a1.z); u1.w = f2bf(a1.w);
    }
    *(ushort4*)(Bp + dbase)     = u0;
    *(ushort4*)(Bp + dbase + 4) = u1;
    if (r < 1024) {
        ss = blockReduce<0>(ss, sbuf);
        if (t == 0) csq[r] = ss;
    }
}

// ---------- prep: W_cos row-normalize -> bf16, zero-pad rows ----------
__global__ void norm_rows(const float* __restrict__ src, u16* __restrict__ dst, int validRows) {
    __shared__ float sbuf[4];
    int r = blockIdx.x, t = threadIdx.x;
    size_t base = (size_t)r * 2048 + t * 8;
    ushort4 u0 = {0,0,0,0}, u1 = {0,0,0,0};
    if (r < validRows) {
        float4 a0 = *(const float4*)(src + base);
        float4 a1 = *(const float4*)(src + base + 4);
        float ss = a0.x*a0.x + a0.y*a0.y + a0.z*a0.z + a0.w*a0.w
                 + a1.x*a1.x + a1.y*a1.y + a1.z*a1.z + a1.w*a1.w;
        ss = blockReduce<0>(ss, sbuf);
        float sc = 1.f / sqrtf(ss);
        u0.x = f2bf(a0.x*sc); u0.y = f2bf(a0.y*sc); u0.z = f2bf(a0.z*sc); u0.w = f2bf(a0.w*sc);
        u1.x = f2bf(a1.x*sc); u1.y = f2bf(a1.y*sc); u1.z = f2bf(a1.z*sc); u1.w = f2bf(a1.w*sc);
    }
    *(ushort4*)(dst + base)     = u0;
    *(ushort4*)(dst + base + 4) = u1;
}

// ---------- prep: centroids [1000,2048] fp32 -> centT [2048,1024] bf16 (transposed, K-padded) ----------
__global__ void transpose_to_bf16(const float* __restrict__ src, u16* __restrict__ dst, int validRows) {
    __shared__ u16 tile[32][33];
    int d0 = blockIdx.x * 32;   // feature base (src col)
    int c0 = blockIdx.y * 32;   // class base  (src row)
    int tx = threadIdx.x, ty = threadIdx.y;
    #pragma unroll
    for (int k = 0; k < 4; ++k) {
        int c = c0 + ty + k * 8;
        float v = (c < validRows) ? src[(size_t)c * 2048 + d0 + tx] : 0.f;
        tile[ty + k * 8][tx] = f2bf(v);
    }
    __syncthreads();
    #pragma unroll
    for (int k = 0; k < 4; ++k) {
        int d = d0 + ty + k * 8;
        dst[(size_t)d * 1024 + c0 + tx] = tile[tx][ty + k * 8];
    }
}

// ---------- GEMM: C[M,N] = A[M,K]bf16 @ Bt[N,K]bf16^T, fp32 accum ----------
// 128x128 tile, BK=64, 256 threads (4 waves 2x2), each wave 64x64 via 4x4 of 16x16x32 MFMA.
// LDS XOR-swizzled (16B granule g of row r holds logical granule g^(r&7)): conflict-free
// while keeping global_load_lds staging segments identical.
// T1: XCD-aware bijective block swizzle (all grids are multiples of 8 workgroups):
// dispatch d (XCD = d%8) -> tile (d%8)*nwg/8 + d/8, so each XCD owns a contiguous
// chunk of row-panels; A-panels become L2-resident, B shared via L3.
// EPI 1: bf16 store to Cb
// EPI 2: acc = memf; inf = tanh(sel[r,c]+bias[c])*acc -> Cf (fp32);
//        fused = reach[r]*(xh[r,c]+inf) -> fusedh (bf16)
// EPI 3: Cf[r,c] = bias[r]*acc  for col < nValid  (bias = per-row CosNorm scale)
template <int EPI>
__global__ __launch_bounds__(256, 4)
void gemm_bt(const u16* __restrict__ A, const u16* __restrict__ Bt,
             float* __restrict__ Cf, u16* __restrict__ Cb,
             int K, int ldc, int nValid,
             const float* __restrict__ bias,
             const u16* __restrict__ selp, int ldsel,
             const float* __restrict__ reach, const u16* __restrict__ xh2,
             u16* __restrict__ fusedh) {
    __shared__ u16 As[128 * 64];
    __shared__ u16 Bs[128 * 64];
    const int tid  = threadIdx.x;
    const int lane = tid & 63;
    const int w    = tid >> 6;
    const int wr   = w >> 1, wc = w & 1;
    const int quad = lane >> 4, r16 = lane & 15;
    const int sw   = r16 & 7;            // reader swizzle key
    const int lr   = lane >> 3;          // staging: row within 8-row chunk (0..7)
    const int lc   = lane & 7;           // staging: physical granule slot (0..7)
    const int lk   = (lc ^ lr) * 8;      // staging: swizzled logical k elem offset

    // T1 XCD swizzle (bijective: nwg % 8 == 0 for all launches here)
    const int nwg = gridDim.x * gridDim.y;
    const int lin = blockIdx.y * gridDim.x + blockIdx.x;
    const int cpx = nwg >> 3;
    const int swz = (lin & 7) * cpx + (lin >> 3);
    const int bx  = swz % gridDim.x;
    const int by  = swz / gridDim.x;
    const size_t rowBase = (size_t)by * 128;
    const size_t colBase = (size_t)bx * 128;

    f32x4 acc[4][4] = {};

    for (int kt = 0; kt < K; kt += 64) {
        #pragma unroll
        for (int i = 0; i < 4; ++i) {
            int ci = w * 4 + i;   // chunk 0..15, 8 rows each
            const u16* ga = A  + (rowBase + ci * 8 + lr) * (size_t)K + kt + lk;
            const u16* gb = Bt + (colBase + ci * 8 + lr) * (size_t)K + kt + lk;
            __builtin_amdgcn_global_load_lds(
                (const __attribute__((address_space(1))) void*)ga,
                (__attribute__((address_space(3))) void*)(As + ci * 512), 16, 0, 0);
            __builtin_amdgcn_global_load_lds(
                (const __attribute__((address_space(1))) void*)gb,
                (__attribute__((address_space(3))) void*)(Bs + ci * 512), 16, 0, 0);
        }
        __syncthreads();
        #pragma unroll
        for (int kk2 = 0; kk2 < 2; ++kk2) {
            // logical granule = kk2*4 + quad; physical = logical ^ sw
            const int off = (((kk2 << 2) | quad) ^ sw) * 8;
            bf16x8 a[4], b[4];
            #pragma unroll
            for (int i = 0; i < 4; ++i)
                a[i] = *(const bf16x8*)(As + (wr * 64 + i * 16 + r16) * 64 + off);
            #pragma unroll
            for (int j = 0; j < 4; ++j)
                b[j] = *(const bf16x8*)(Bs + (wc * 64 + j * 16 + r16) * 64 + off);
            #pragma unroll
            for (int i = 0; i < 4; ++i)
                #pragma unroll
                for (int j = 0; j < 4; ++j)
                    acc[i][j] = __builtin_amdgcn_mfma_f32_16x16x32_bf16(a[i], b[j], acc[i][j], 0, 0, 0);
        }
        __syncthreads();
    }

    // epilogue: C/D layout col=lane&15, row=quad*4+reg (verified m89/m91)
    #pragma unroll
    for (int i = 0; i < 4; ++i) {
        #pragma unroll
        for (int j = 0; j < 4; ++j) {
            #pragma unroll
            for (int v = 0; v < 4; ++v) {
                size_t grow = rowBase + wr * 64 + i * 16 + quad * 4 + v;
                size_t gcol = colBase + wc * 64 + j * 16 + r16;
                float val = acc[i][j][v];
                if (EPI == 1) {
                    Cb[grow * (size_t)ldc + gcol] = f2bf(val);
                } else if (EPI == 2) {
                    float sv  = bf2f(selp[grow * (size_t)ldsel + gcol]);
                    float t   = tanhf(sv + bias[gcol]);
                    float inf = t * val;
                    Cf[grow * (size_t)ldc + gcol] = inf;
                    float xv = bf2f(xh2[grow * (size_t)ldc + gcol]);
                    fusedh[grow * (size_t)ldc + gcol] = f2bf(reach[grow] * (xv + inf));
                } else if (EPI == 3) {
                    if ((int)gcol < nValid) Cf[grow * (size_t)ldc + gcol] = bias[grow] * val;
                }
            }
        }
    }
}

// ---------- merged: min distance -> reachability, softmax -> Vm ----------
// Sp is [B,4096] bf16: cols 0..999 = x.cent, 1024..2023 = x.W_hall (2048..4095 = sel, unused here)
__global__ void min_softmax(const u16* __restrict__ Sp, const float* __restrict__ xsq,
                            const float* __restrict__ csq, const float* __restrict__ bh,
                            float* __restrict__ reach, u16* __restrict__ Vm) {
    __shared__ float sbuf[4];
    int r = blockIdx.x, t = threadIdx.x;
    size_t rb = (size_t)r * 4096;
    // --- min distance ---
    float m = 1e30f;
    for (int c = t; c < 1000; c += 256)
        m = fminf(m, csq[c] - 2.f * bf2f(Sp[rb + c]));
    m = blockReduce<2>(m, sbuf);
    if (t == 0) {
        float d2 = xsq[r] + m;
        reach[r] = 10.f / sqrtf(fmaxf(d2, 0.f));
    }
    // --- softmax over 1000 classes ---
    float l[4];
    float mx = -1e30f;
    #pragma unroll
    for (int i = 0; i < 4; ++i) {
        int c = t + i * 256;
        l[i] = (c < 1000) ? (bf2f(Sp[rb + 1024 + c]) + bh[c]) : -1e30f;
        mx = fmaxf(mx, l[i]);
    }
    mx = blockReduce<1>(mx, sbuf);
    float s = 0.f;
    #pragma unroll
    for (int i = 0; i < 4; ++i) {
        int c = t + i * 256;
        l[i] = (c < 1000) ? expf(l[i] - mx) : 0.f;
        s += l[i];
    }
    s = blockReduce<0>(s, sbuf);
    float inv = 1.f / s;
    #pragma unroll
    for (int i = 0; i < 4; ++i) {
        int c = t + i * 256;
        Vm[(size_t)r * 1024 + c] = f2bf(l[i] * inv);
    }
}

// ---------- per-row CosNorm scale: scale[r] = 16/(1+||fused_r||) ----------
__global__ void rowsq_scale(const u16* __restrict__ fusedh, float* __restrict__ scale) {
    __shared__ float sbuf[4];
    int r = blockIdx.x, t = threadIdx.x;
    size_t base = (size_t)r * 2048 + t * 8;
    ushort4 u0 = *(const ushort4*)(fusedh + base);
    ushort4 u1 = *(const ushort4*)(fusedh + base + 4);
    float f0 = bf2f(u0.x), f1 = bf2f(u0.y), f2 = bf2f(u0.z), f3 = bf2f(u0.w);
    float f4 = bf2f(u1.x), f5 = bf2f(u1.y), f6 = bf2f(u1.z), f7 = bf2f(u1.w);
    float ss = f0*f0 + f1*f1 + f2*f2 + f3*f3 + f4*f4 + f5*f5 + f6*f6 + f7*f7;
    ss = blockReduce<0>(ss, sbuf);
    if (t == 0) scale[r] = 16.f / (1.f + sqrtf(ss));
}

extern "C" void kernel_launch(void* const* d_in, const int* in_sizes, int n_in,
                              void* d_out, int out_size, void* d_ws, size_t ws_size,
                              hipStream_t stream) {
    const float* x      = (const float*)d_in[0];   // [8192,2048]
    const float* cent   = (const float*)d_in[1];   // [1000,2048]
    const float* W_hall = (const float*)d_in[2];   // [1000,2048]
    const float* b_hall = (const float*)d_in[3];   // [1000]
    const float* W_sel  = (const float*)d_in[4];   // [2048,2048]
    const float* b_sel  = (const float*)d_in[5];   // [2048]
    const float* W_cos  = (const float*)d_in[6];   // [1000,2048]

    float* out_logits = (float*)d_out;                          // [8192,1000]
    float* out_x      = out_logits + (size_t)8192 * 1000;       // [8192,2048]
    float* out_inf    = out_x      + (size_t)8192 * 2048;       // [8192,2048]

    char* ws = (char*)d_ws;
    u16*   xh     = (u16*)  (ws);                  // 33554432 B  [8192,2048] bf16
    u16*   Bp     = (u16*)  (ws + 33554432);       // 16777216 B  [4096,2048] bf16: cent|W_hall|W_sel
    u16*   ew     = (u16*)  (ws + 50331648);       //  4194304 B  [1024,2048]
    u16*   centT  = (u16*)  (ws + 54525952);       //  4194304 B  [2048,1024]
    u16*   Sp     = (u16*)  (ws + 58720256);       // 67108864 B  [8192,4096] bf16 (dot|H|sel)
    u16*   Vm     = (u16*)  (ws + 125829120);      // 16777216 B  [8192,1024] bf16
    u16*   fusedh = (u16*)  (ws + 142606336);      // 33554432 B  [8192,2048] bf16
    float* xsq    = (float*)(ws + 176160768);      //    32768 B
    float* csq    = (float*)(ws + 176193536);      //     4096 B
    float* reach  = (float*)(ws + 176197632);      //    32768 B
    float* scale  = (float*)(ws + 176230400);      //    32768 B

    (void)in_sizes; (void)n_in; (void)out_size; (void)ws_size;

    // prep (convert_x also streams the fp32 passthrough to out_x: direct_feature)
    convert_x<<<8192, 256, 0, stream>>>(x, xh, xsq, out_x);
    convert_weights<<<4096, 256, 0, stream>>>(cent, W_hall, W_sel, Bp, csq);
    norm_rows<<<1024, 256, 0, stream>>>(W_cos, ew, 1000);
    transpose_to_bf16<<<dim3(64, 32), dim3(32, 8), 0, stream>>>(cent, centT, 1000);

    // GEMM-A: Sp = x @ [cent | W_hall | W_sel]^T  (N=4096, bf16 out)  nwg=2048
    gemm_bt<1><<<dim3(32, 64), 256, 0, stream>>>(xh, Bp, nullptr, Sp, 2048, 4096, 0,
                                                 nullptr, nullptr, 0, nullptr, nullptr, nullptr);
    min_softmax<<<8192, 256, 0, stream>>>(Sp, xsq, csq, b_hall, reach, Vm);

    // GEMM-B: acc = Vm @ cent (memf); epilogue: inf=tanh(sel+b_sel)*acc -> out_inf,
    //         fused=reach*(x+inf) -> fusedh   nwg=1024
    gemm_bt<2><<<dim3(16, 64), 256, 0, stream>>>(Vm, centT, out_inf, nullptr, 1024, 2048, 0,
                                                 b_sel, Sp + 2048, 4096, reach, xh, fusedh);

    // per-row CosNorm scale
    rowsq_scale<<<8192, 256, 0, stream>>>(fusedh, scale);

    // GEMM-C: logits = scale[row] * (fused @ ew^T)  (store only cols < 1000)  nwg=512
    gemm_bt<3><<<dim3(8, 64), 256, 0, stream>>>(fusedh, ew, out_logits, nullptr, 2048, 1000, 1000,
                                                scale, nullptr, 0, nullptr, nullptr, nullptr);
}

// Round 3
// 516.786 us; speedup vs baseline: 1.1781x; 1.0877x over previous
//
#include <hip/hip_runtime.h>
#include <hip/hip_bf16.h>

// ---------- types ----------
typedef __bf16 bf16x8 __attribute__((ext_vector_type(8)));
typedef float  f32x4  __attribute__((ext_vector_type(4)));
typedef unsigned short u16;

__device__ __forceinline__ u16 f2bf(float f) {
    __hip_bfloat16 h = __float2bfloat16(f);   // RNE
    return __builtin_bit_cast(unsigned short, h);
}
__device__ __forceinline__ float bf2f(u16 u) {
    return __bfloat162float(__builtin_bit_cast(__hip_bfloat16, u));
}

// mode: 0=sum, 1=max, 2=min   (256-thread blocks = 4 waves)
template <int MODE>
__device__ __forceinline__ float blockReduce(float v, float* sbuf) {
    #pragma unroll
    for (int off = 32; off > 0; off >>= 1) {
        float o = __shfl_down(v, off, 64);
        v = (MODE == 0) ? v + o : (MODE == 1) ? fmaxf(v, o) : fminf(v, o);
    }
    int lane = threadIdx.x & 63, w = threadIdx.x >> 6;
    __syncthreads();                 // protect sbuf from previous use
    if (lane == 0) sbuf[w] = v;
    __syncthreads();
    float r = sbuf[0];
    #pragma unroll
    for (int i = 1; i < 4; ++i) {
        float o = sbuf[i];
        r = (MODE == 0) ? r + o : (MODE == 1) ? fmaxf(r, o) : fminf(r, o);
    }
    return r;
}

// ---------- prep: x fp32 -> xh bf16 + xsq + fp32 passthrough to out_x ----------
// also zero-inits scaleAcc[r] (per-row fused^2 accumulator used by GEMM-B/C)
__global__ void convert_x(const float* __restrict__ src, u16* __restrict__ dst,
                          float* __restrict__ rowsq, float* __restrict__ copyOut,
                          float* __restrict__ scaleAcc) {
    __shared__ float sbuf[4];
    int r = blockIdx.x, t = threadIdx.x;
    size_t base = (size_t)r * 2048 + t * 8;
    float4 a0 = *(const float4*)(src + base);
    float4 a1 = *(const float4*)(src + base + 4);
    float ss = a0.x*a0.x + a0.y*a0.y + a0.z*a0.z + a0.w*a0.w
             + a1.x*a1.x + a1.y*a1.y + a1.z*a1.z + a1.w*a1.w;
    ushort4 u0, u1;
    u0.x = f2bf(a0.x); u0.y = f2bf(a0.y); u0.z = f2bf(a0.z); u0.w = f2bf(a0.w);
    u1.x = f2bf(a1.x); u1.y = f2bf(a1.y); u1.z = f2bf(a1.z); u1.w = f2bf(a1.w);
    *(ushort4*)(dst + base)     = u0;
    *(ushort4*)(dst + base + 4) = u1;
    *(float4*)(copyOut + base)     = a0;
    *(float4*)(copyOut + base + 4) = a1;
    ss = blockReduce<0>(ss, sbuf);
    if (t == 0) {
        rowsq[r] = ss;
        scaleAcc[r] = 0.f;   // re-zeroed every graph replay, before GEMM-B
    }
}

// ---------- prep: merged weight convert -> Bp [4096,2048] bf16 (+ W_cos normalize) ----------
// blocks 0..1023 = cent (valid<1000, csq), 1024..2047 = W_hall (valid<1000),
// 2048..4095 = W_sel, 4096..5119 = W_cos row-normalize -> ew (zero-pad rows >=1000)
__global__ void convert_weights(const float* __restrict__ cent, const float* __restrict__ whall,
                                const float* __restrict__ wsel, u16* __restrict__ Bp,
                                float* __restrict__ csq,
                                const float* __restrict__ wcos, u16* __restrict__ ew) {
    __shared__ float sbuf[4];
    int r = blockIdx.x, t = threadIdx.x;
    if (r >= 4096) {
        // --- norm_rows path: W_cos row r' -> ew, row-normalized bf16 ---
        int rr = r - 4096;
        size_t base = (size_t)rr * 2048 + t * 8;
        ushort4 u0 = {0,0,0,0}, u1 = {0,0,0,0};
        if (rr < 1000) {
            float4 a0 = *(const float4*)(wcos + base);
            float4 a1 = *(const float4*)(wcos + base + 4);
            float ss = a0.x*a0.x + a0.y*a0.y + a0.z*a0.z + a0.w*a0.w
                     + a1.x*a1.x + a1.y*a1.y + a1.z*a1.z + a1.w*a1.w;
            ss = blockReduce<0>(ss, sbuf);
            float sc = 1.f / sqrtf(ss);
            u0.x = f2bf(a0.x*sc); u0.y = f2bf(a0.y*sc); u0.z = f2bf(a0.z*sc); u0.w = f2bf(a0.w*sc);
            u1.x = f2bf(a1.x*sc); u1.y = f2bf(a1.y*sc); u1.z = f2bf(a1.z*sc); u1.w = f2bf(a1.w*sc);
        }
        *(ushort4*)(ew + base)     = u0;
        *(ushort4*)(ew + base + 4) = u1;
        return;
    }
    const float* src; int sr; bool valid;
    if (r < 1024)       { src = cent;  sr = r;        valid = sr < 1000; }
    else if (r < 2048)  { src = whall; sr = r - 1024; valid = sr < 1000; }
    else                { src = wsel;  sr = r - 2048; valid = true; }
    size_t dbase = (size_t)r * 2048 + t * 8;
    float ss = 0.f;
    ushort4 u0 = {0,0,0,0}, u1 = {0,0,0,0};
    if (valid) {
        size_t sbase = (size_t)sr * 2048 + t * 8;
        float4 a0 = *(const float4*)(src + sbase);
        float4 a1 = *(const float4*)(src + sbase + 4);
        ss = a0.x*a0.x + a0.y*a0.y + a0.z*a0.z + a0.w*a0.w
           + a1.x*a1.x + a1.y*a1.y + a1.z*a1.z + a1.w*a1.w;
        u0.x = f2bf(a0.x); u0.y = f2bf(a0.y); u0.z = f2bf(a0.z); u0.w = f2bf(a0.w);
        u1.x = f2bf(a1.x); u1.y = f2bf(a1.y); u1.z = f2bf(a1.z); u1.w = f2bf(a1.w);
    }
    *(ushort4*)(Bp + dbase)     = u0;
    *(ushort4*)(Bp + dbase + 4) = u1;
    if (r < 1024) {
        ss = blockReduce<0>(ss, sbuf);
        if (t == 0) csq[r] = ss;
    }
}

// ---------- prep: centroids [1000,2048] fp32 -> centT [2048,1024] bf16 (transposed, K-padded) ----------
__global__ void transpose_to_bf16(const float* __restrict__ src, u16* __restrict__ dst, int validRows) {
    __shared__ u16 tile[32][33];
    int d0 = blockIdx.x * 32;   // feature base (src col)
    int c0 = blockIdx.y * 32;   // class base  (src row)
    int tx = threadIdx.x, ty = threadIdx.y;
    #pragma unroll
    for (int k = 0; k < 4; ++k) {
        int c = c0 + ty + k * 8;
        float v = (c < validRows) ? src[(size_t)c * 2048 + d0 + tx] : 0.f;
        tile[ty + k * 8][tx] = f2bf(v);
    }
    __syncthreads();
    #pragma unroll
    for (int k = 0; k < 4; ++k) {
        int d = d0 + ty + k * 8;
        dst[(size_t)d * 1024 + c0 + tx] = tile[tx][ty + k * 8];
    }
}

// ---------- GEMM: C[M,N] = A[M,K]bf16 @ Bt[N,K]bf16^T, fp32 accum ----------
// 128x128 tile, BK=64, 256 threads (4 waves 2x2), each wave 64x64 via 4x4 of 16x16x32 MFMA.
// LDS XOR-swizzled (16B granule g of row r holds logical granule g^(r&7)): conflict-free
// while keeping global_load_lds staging segments identical.
// NOTE: default linear block order is already XCD-optimal for these grids
// (XCD = bx%8 keeps 4 B-col-panels L2-resident per XCD; A streams via L3
// temporally aligned across XCDs). Measured: remapping regressed (R2: FETCH
// 161MB -> 410MB). Do not swizzle blockIdx here.
// EPI 1: bf16 store to Cb
// EPI 2: acc = memf; inf = tanh(sel[r,c]+bias[c])*acc -> Cf (fp32);
//        fused = reach[r]*(xh[r,c]+inf) -> fusedh (bf16);
//        scaleAcc[row] += sum(fused^2)  (shfl-reduced, 1 atomic per row-quad)
// EPI 3: Cf[r,c] = (16/(1+sqrt(bias[r]))) * acc  for col < nValid
template <int EPI>
__global__ __launch_bounds__(256, 4)
void gemm_bt(const u16* __restrict__ A, const u16* __restrict__ Bt,
             float* __restrict__ Cf, u16* __restrict__ Cb,
             int K, int ldc, int nValid,
             const float* __restrict__ bias,
             const u16* __restrict__ selp, int ldsel,
             const float* __restrict__ reach, const u16* __restrict__ xh2,
             u16* __restrict__ fusedh, float* __restrict__ scaleAcc) {
    __shared__ u16 As[128 * 64];
    __shared__ u16 Bs[128 * 64];
    const int tid  = threadIdx.x;
    const int lane = tid & 63;
    const int w    = tid >> 6;
    const int wr   = w >> 1, wc = w & 1;
    const int quad = lane >> 4, r16 = lane & 15;
    const int sw   = r16 & 7;            // reader swizzle key
    const int lr   = lane >> 3;          // staging: row within 8-row chunk (0..7)
    const int lc   = lane & 7;           // staging: physical granule slot (0..7)
    const int lk   = (lc ^ lr) * 8;      // staging: swizzled logical k elem offset
    const size_t rowBase = (size_t)blockIdx.y * 128;
    const size_t colBase = (size_t)blockIdx.x * 128;

    f32x4 acc[4][4] = {};

    for (int kt = 0; kt < K; kt += 64) {
        #pragma unroll
        for (int i = 0; i < 4; ++i) {
            int ci = w * 4 + i;   // chunk 0..15, 8 rows each
            const u16* ga = A  + (rowBase + ci * 8 + lr) * (size_t)K + kt + lk;
            const u16* gb = Bt + (colBase + ci * 8 + lr) * (size_t)K + kt + lk;
            __builtin_amdgcn_global_load_lds(
                (const __attribute__((address_space(1))) void*)ga,
                (__attribute__((address_space(3))) void*)(As + ci * 512), 16, 0, 0);
            __builtin_amdgcn_global_load_lds(
                (const __attribute__((address_space(1))) void*)gb,
                (__attribute__((address_space(3))) void*)(Bs + ci * 512), 16, 0, 0);
        }
        __syncthreads();
        #pragma unroll
        for (int kk2 = 0; kk2 < 2; ++kk2) {
            // logical granule = kk2*4 + quad; physical = logical ^ sw
            const int off = (((kk2 << 2) | quad) ^ sw) * 8;
            bf16x8 a[4], b[4];
            #pragma unroll
            for (int i = 0; i < 4; ++i)
                a[i] = *(const bf16x8*)(As + (wr * 64 + i * 16 + r16) * 64 + off);
            #pragma unroll
            for (int j = 0; j < 4; ++j)
                b[j] = *(const bf16x8*)(Bs + (wc * 64 + j * 16 + r16) * 64 + off);
            #pragma unroll
            for (int i = 0; i < 4; ++i)
                #pragma unroll
                for (int j = 0; j < 4; ++j)
                    acc[i][j] = __builtin_amdgcn_mfma_f32_16x16x32_bf16(a[i], b[j], acc[i][j], 0, 0, 0);
        }
        __syncthreads();
    }

    // epilogue: C/D layout col=lane&15, row=quad*4+reg (verified m89/m91)
    if (EPI == 2) {
        #pragma unroll
        for (int i = 0; i < 4; ++i) {
            #pragma unroll
            for (int v = 0; v < 4; ++v) {
                size_t grow = rowBase + wr * 64 + i * 16 + quad * 4 + v;
                float rch = reach[grow];
                float rs = 0.f;
                #pragma unroll
                for (int j = 0; j < 4; ++j) {
                    size_t gcol = colBase + wc * 64 + j * 16 + r16;
                    float val = acc[i][j][v];
                    float sv  = bf2f(selp[grow * (size_t)ldsel + gcol]);
                    float t   = tanhf(sv + bias[gcol]);
                    float inf = t * val;
                    Cf[grow * (size_t)ldc + gcol] = inf;
                    float xv = bf2f(xh2[grow * (size_t)ldc + gcol]);
                    float fs = rch * (xv + inf);
                    fusedh[grow * (size_t)ldc + gcol] = f2bf(fs);
                    rs += fs * fs;
                }
                // lanes of one quad (r16=0..15) share this row; reduce & one atomic
                #pragma unroll
                for (int off = 8; off > 0; off >>= 1)
                    rs += __shfl_down(rs, off, 16);
                if (r16 == 0) atomicAdd(&scaleAcc[grow], rs);
            }
        }
    } else {
        #pragma unroll
        for (int i = 0; i < 4; ++i) {
            #pragma unroll
            for (int j = 0; j < 4; ++j) {
                #pragma unroll
                for (int v = 0; v < 4; ++v) {
                    size_t grow = rowBase + wr * 64 + i * 16 + quad * 4 + v;
                    size_t gcol = colBase + wc * 64 + j * 16 + r16;
                    float val = acc[i][j][v];
                    if (EPI == 1) {
                        Cb[grow * (size_t)ldc + gcol] = f2bf(val);
                    } else if (EPI == 3) {
                        if ((int)gcol < nValid) {
                            float sc = 16.f / (1.f + sqrtf(bias[grow]));
                            Cf[grow * (size_t)ldc + gcol] = sc * val;
                        }
                    }
                }
            }
        }
    }
}

// ---------- merged: min distance -> reachability, softmax -> Vm ----------
// Sp is [B,4096] bf16: cols 0..999 = x.cent, 1024..2023 = x.W_hall (2048..4095 = sel, unused here)
// vectorized: thread t handles classes 4t..4t+3 (t<250); t in [250,256) zero-pads Vm
__global__ void min_softmax(const u16* __restrict__ Sp, const float* __restrict__ xsq,
                            const float* __restrict__ csq, const float* __restrict__ bh,
                            float* __restrict__ reach, u16* __restrict__ Vm) {
    __shared__ float sbuf[4];
    int r = blockIdx.x, t = threadIdx.x;
    size_t rb = (size_t)r * 4096;
    int c0 = t * 4;
    // --- min distance ---
    float m = 1e30f;
    if (t < 250) {
        ushort4 d4 = *(const ushort4*)(Sp + rb + c0);
        m = fminf(fminf(csq[c0+0] - 2.f * bf2f(d4.x), csq[c0+1] - 2.f * bf2f(d4.y)),
                  fminf(csq[c0+2] - 2.f * bf2f(d4.z), csq[c0+3] - 2.f * bf2f(d4.w)));
    }
    m = blockReduce<2>(m, sbuf);
    if (t == 0) {
        float d2 = xsq[r] + m;
        reach[r] = 10.f / sqrtf(fmaxf(d2, 0.f));
    }
    // --- softmax over 1000 classes ---
    float l[4];
    float mx = -1e30f;
    if (t < 250) {
        ushort4 h4 = *(const ushort4*)(Sp + rb + 1024 + c0);
        l[0] = bf2f(h4.x) + bh[c0+0];
        l[1] = bf2f(h4.y) + bh[c0+1];
        l[2] = bf2f(h4.z) + bh[c0+2];
        l[3] = bf2f(h4.w) + bh[c0+3];
        mx = fmaxf(fmaxf(l[0], l[1]), fmaxf(l[2], l[3]));
    } else {
        l[0] = l[1] = l[2] = l[3] = -1e30f;
    }
    mx = blockReduce<1>(mx, sbuf);
    float s = 0.f;
    #pragma unroll
    for (int i = 0; i < 4; ++i) {
        l[i] = (t < 250) ? expf(l[i] - mx) : 0.f;
        s += l[i];
    }
    s = blockReduce<0>(s, sbuf);
    float inv = 1.f / s;
    ushort4 o;
    o.x = f2bf(l[0] * inv); o.y = f2bf(l[1] * inv);
    o.z = f2bf(l[2] * inv); o.w = f2bf(l[3] * inv);
    *(ushort4*)(Vm + (size_t)r * 1024 + c0) = o;   // t>=250 stores zeros (pads 1000..1023)
}

extern "C" void kernel_launch(void* const* d_in, const int* in_sizes, int n_in,
                              void* d_out, int out_size, void* d_ws, size_t ws_size,
                              hipStream_t stream) {
    const float* x      = (const float*)d_in[0];   // [8192,2048]
    const float* cent   = (const float*)d_in[1];   // [1000,2048]
    const float* W_hall = (const float*)d_in[2];   // [1000,2048]
    const float* b_hall = (const float*)d_in[3];   // [1000]
    const float* W_sel  = (const float*)d_in[4];   // [2048,2048]
    const float* b_sel  = (const float*)d_in[5];   // [2048]
    const float* W_cos  = (const float*)d_in[6];   // [1000,2048]

    float* out_logits = (float*)d_out;                          // [8192,1000]
    float* out_x      = out_logits + (size_t)8192 * 1000;       // [8192,2048]
    float* out_inf    = out_x      + (size_t)8192 * 2048;       // [8192,2048]

    char* ws = (char*)d_ws;
    u16*   xh     = (u16*)  (ws);                  // 33554432 B  [8192,2048] bf16
    u16*   Bp     = (u16*)  (ws + 33554432);       // 16777216 B  [4096,2048] bf16: cent|W_hall|W_sel
    u16*   ew     = (u16*)  (ws + 50331648);       //  4194304 B  [1024,2048]
    u16*   centT  = (u16*)  (ws + 54525952);       //  4194304 B  [2048,1024]
    u16*   Sp     = (u16*)  (ws + 58720256);       // 67108864 B  [8192,4096] bf16 (dot|H|sel)
    u16*   Vm     = (u16*)  (ws + 125829120);      // 16777216 B  [8192,1024] bf16
    u16*   fusedh = (u16*)  (ws + 142606336);      // 33554432 B  [8192,2048] bf16
    float* xsq    = (float*)(ws + 176160768);      //    32768 B
    float* csq    = (float*)(ws + 176193536);      //     4096 B
    float* reach  = (float*)(ws + 176197632);      //    32768 B
    float* scale  = (float*)(ws + 176230400);      //    32768 B  (raw sum(fused^2) per row)

    (void)in_sizes; (void)n_in; (void)out_size; (void)ws_size;

    // prep (convert_x also streams the fp32 passthrough to out_x and zeroes scale)
    convert_x<<<8192, 256, 0, stream>>>(x, xh, xsq, out_x, scale);
    convert_weights<<<5120, 256, 0, stream>>>(cent, W_hall, W_sel, Bp, csq, W_cos, ew);
    transpose_to_bf16<<<dim3(64, 32), dim3(32, 8), 0, stream>>>(cent, centT, 1000);

    // GEMM-A: Sp = x @ [cent | W_hall | W_sel]^T  (N=4096, bf16 out)
    gemm_bt<1><<<dim3(32, 64), 256, 0, stream>>>(xh, Bp, nullptr, Sp, 2048, 4096, 0,
                                                 nullptr, nullptr, 0, nullptr, nullptr, nullptr, nullptr);
    min_softmax<<<8192, 256, 0, stream>>>(Sp, xsq, csq, b_hall, reach, Vm);

    // GEMM-B: acc = Vm @ cent (memf); epilogue: inf=tanh(sel+b_sel)*acc -> out_inf,
    //         fused=reach*(x+inf) -> fusedh, scale[row] += sum(fused^2)
    gemm_bt<2><<<dim3(16, 64), 256, 0, stream>>>(Vm, centT, out_inf, nullptr, 1024, 2048, 0,
                                                 b_sel, Sp + 2048, 4096, reach, xh, fusedh, scale);

    // GEMM-C: logits = (16/(1+sqrt(scale[row]))) * (fused @ ew^T)  (store only cols < 1000)
    gemm_bt<3><<<dim3(8, 64), 256, 0, stream>>>(fusedh, ew, out_logits, nullptr, 2048, 1000, 1000,
                                                scale, nullptr, 0, nullptr, nullptr, nullptr, nullptr);
}